// Round 1
// baseline (30.921 us; speedup 1.0000x reference)
//
#include <hip/hip_runtime.h>
#include <math.h>

#define NPTS 4096
#define BLOCK 256
#define PTS4 (NPTS / 2)            // number of float4 (2 points each)
#define ITERS (PTS4 / BLOCK)       // 8

__global__ __launch_bounds__(BLOCK) void geo_mlp_kernel(
    const float* __restrict__ points,  // (B, N, 2)
    const float* __restrict__ W1,      // (10, 64)
    const float* __restrict__ b1,      // (64)
    const float* __restrict__ W2,      // (64, 32)
    const float* __restrict__ b2,      // (32)
    float* __restrict__ out)           // (B, 32)
{
    __shared__ float4 pts[PTS4];       // 32 KiB point stage
    __shared__ float wred[4][10];      // per-wave partials
    __shared__ float h[64];            // hidden layer

    const int tid  = threadIdx.x;
    const int lane = tid & 63;
    const int wave = tid >> 6;
    const int b    = blockIdx.x;

    const float4* __restrict__ src =
        (const float4*)(points + (size_t)b * NPTS * 2);

    // ---- pass 1: global -> LDS stage + moment/minmax accumulation ----
    float minx =  INFINITY, miny =  INFINITY;
    float maxx = -INFINITY, maxy = -INFINITY;
    float sx = 0.f, sy = 0.f, sxx = 0.f, syy = 0.f;

    #pragma unroll
    for (int i = 0; i < ITERS; ++i) {
        const int idx = tid + i * BLOCK;
        float4 v = src[idx];
        pts[idx] = v;
        minx = fminf(minx, fminf(v.x, v.z));
        maxx = fmaxf(maxx, fmaxf(v.x, v.z));
        miny = fminf(miny, fminf(v.y, v.w));
        maxy = fmaxf(maxy, fmaxf(v.y, v.w));
        sx += v.x + v.z;
        sy += v.y + v.w;
        sxx = fmaf(v.x, v.x, sxx); sxx = fmaf(v.z, v.z, sxx);
        syy = fmaf(v.y, v.y, syy); syy = fmaf(v.w, v.w, syy);
    }

    // wave (64-lane) reduction
    #pragma unroll
    for (int off = 32; off > 0; off >>= 1) {
        minx = fminf(minx, __shfl_down(minx, off));
        maxx = fmaxf(maxx, __shfl_down(maxx, off));
        miny = fminf(miny, __shfl_down(miny, off));
        maxy = fmaxf(maxy, __shfl_down(maxy, off));
        sx  += __shfl_down(sx,  off);
        sy  += __shfl_down(sy,  off);
        sxx += __shfl_down(sxx, off);
        syy += __shfl_down(syy, off);
    }
    if (lane == 0) {
        wred[wave][0] = minx; wred[wave][1] = maxx;
        wred[wave][2] = miny; wred[wave][3] = maxy;
        wred[wave][4] = sx;   wred[wave][5] = sy;
        wred[wave][6] = sxx;  wred[wave][7] = syy;
    }
    __syncthreads();

    // all threads combine the 4 wave partials (broadcast LDS reads, cheap)
    float fminx = fminf(fminf(wred[0][0], wred[1][0]), fminf(wred[2][0], wred[3][0]));
    float fmaxx = fmaxf(fmaxf(wred[0][1], wred[1][1]), fmaxf(wred[2][1], wred[3][1]));
    float fminy = fminf(fminf(wred[0][2], wred[1][2]), fminf(wred[2][2], wred[3][2]));
    float fmaxy = fmaxf(fmaxf(wred[0][3], wred[1][3]), fmaxf(wred[2][3], wred[3][3]));
    float fsx  = (wred[0][4] + wred[1][4]) + (wred[2][4] + wred[3][4]);
    float fsy  = (wred[0][5] + wred[1][5]) + (wred[2][5] + wred[3][5]);
    float fsxx = (wred[0][6] + wred[1][6]) + (wred[2][6] + wred[3][6]);
    float fsyy = (wred[0][7] + wred[1][7]) + (wred[2][7] + wred[3][7]);

    const float invN = 1.0f / (float)NPTS;
    const float cx = fsx * invN;
    const float cy = fsy * invN;

    // ---- pass 2: distances from LDS ----
    float sd = 0.f, sd2 = 0.f;
    #pragma unroll
    for (int i = 0; i < ITERS; ++i) {
        float4 v = pts[tid + i * BLOCK];
        float dx0 = v.x - cx, dy0 = v.y - cy;
        float dx1 = v.z - cx, dy1 = v.w - cy;
        float d0 = sqrtf(fmaf(dx0, dx0, dy0 * dy0));
        float d1 = sqrtf(fmaf(dx1, dx1, dy1 * dy1));
        sd += d0 + d1;
        sd2 = fmaf(d0, d0, sd2);
        sd2 = fmaf(d1, d1, sd2);
    }
    #pragma unroll
    for (int off = 32; off > 0; off >>= 1) {
        sd  += __shfl_down(sd,  off);
        sd2 += __shfl_down(sd2, off);
    }
    if (lane == 0) {
        wred[wave][8] = sd;
        wred[wave][9] = sd2;
    }
    __syncthreads();

    // ---- MLP layer 1: 64 threads, each one hidden unit ----
    if (tid < 64) {
        float fsd  = (wred[0][8] + wred[1][8]) + (wred[2][8] + wred[3][8]);
        float fsd2 = (wred[0][9] + wred[1][9]) + (wred[2][9] + wred[3][9]);
        float dist_mean = fsd * invN;
        float dist_std  = sqrtf(fmaxf(fsd2 * invN - dist_mean * dist_mean, 0.f));
        float stdx = sqrtf(fmaxf(fsxx * invN - cx * cx, 0.f));
        float stdy = sqrtf(fmaxf(fsyy * invN - cy * cy, 0.f));

        float g[10];
        g[0] = (fminx + fmaxx) * 0.5f;   // bbox_center.x
        g[1] = (fminy + fmaxy) * 0.5f;   // bbox_center.y
        g[2] = fmaxx - fminx;            // bbox_size.x
        g[3] = fmaxy - fminy;            // bbox_size.y
        g[4] = cx;                       // centroid.x
        g[5] = cy;                       // centroid.y
        g[6] = stdx;                     // std.x
        g[7] = stdy;                     // std.y
        g[8] = dist_mean;
        g[9] = dist_std;

        float acc = b1[tid];
        #pragma unroll
        for (int i = 0; i < 10; ++i)
            acc = fmaf(g[i], W1[i * 64 + tid], acc);
        h[tid] = fmaxf(acc, 0.f);
    }
    __syncthreads();

    // ---- MLP layer 2: 32 threads, each one output unit ----
    if (tid < 32) {
        float acc = b2[tid];
        #pragma unroll
        for (int i = 0; i < 64; ++i)
            acc = fmaf(h[i], W2[i * 32 + tid], acc);
        out[(size_t)b * 32 + tid] = fmaxf(acc, 0.f);
    }
}

extern "C" void kernel_launch(void* const* d_in, const int* in_sizes, int n_in,
                              void* d_out, int out_size, void* d_ws, size_t ws_size,
                              hipStream_t stream) {
    const float* points = (const float*)d_in[0];
    const float* W1     = (const float*)d_in[1];
    const float* b1     = (const float*)d_in[2];
    const float* W2     = (const float*)d_in[3];
    const float* b2     = (const float*)d_in[4];
    float* out          = (float*)d_out;

    const int B = in_sizes[0] / (NPTS * 2);   // 4096
    geo_mlp_kernel<<<B, BLOCK, 0, stream>>>(points, W1, b1, W2, b2, out);
}